// Round 3
// baseline (27292.154 us; speedup 1.0000x reference)
//
#include <hip/hip_runtime.h>
#include <hip/hip_bf16.h>

#define T_ 512
#define B_ 64
#define IN_ 512
#define H_ 1024
#define G4_ 4096

typedef unsigned short u16;
typedef unsigned int u32;
typedef __attribute__((ext_vector_type(8))) short short8;
typedef __attribute__((ext_vector_type(4))) float f32x4;

__device__ __forceinline__ float sigm(float x) { return 1.0f / (1.0f + __expf(-x)); }
__device__ __forceinline__ float ftanh(float x) {
    float e = __expf(-2.0f * fabsf(x));
    float t = (1.0f - e) / (1.0f + e);
    return copysignf(t, x);
}
__device__ __forceinline__ u16 f2bf(float f) {
    unsigned int x = __float_as_uint(f);
    return (u16)((x + 0x7FFFu + ((x >> 16) & 1u)) >> 16);
}

// fp32 -> bf16 convert, 4 elems/thread (all n are multiples of 4)
__global__ void f2b_kernel(const float* __restrict__ in, u16* __restrict__ out, int n) {
    int i = (blockIdx.x * blockDim.x + threadIdx.x) * 4;
    if (i < n) {
        float4 v = *reinterpret_cast<const float4*>(in + i);
        out[i + 0] = f2bf(v.x);
        out[i + 1] = f2bf(v.y);
        out[i + 2] = f2bf(v.z);
        out[i + 3] = f2bf(v.w);
    }
}

__global__ void bias_sum_kernel(const float* __restrict__ bih0, const float* __restrict__ bhh0,
                                const float* __restrict__ bih1, const float* __restrict__ bhh1,
                                float* __restrict__ bs0, float* __restrict__ bs1) {
    int i = blockIdx.x * blockDim.x + threadIdx.x;
    if (i < G4_) {
        bs0[i] = bih0[i] + bhh0[i];
        bs1[i] = bih1[i] + bhh1[i];
    }
}

// One spinner per block polls the device-scope counter, then a single
// agent fence (buffer_inv) before __syncthreads releases the block.
__device__ __forceinline__ void spin_wait(u32* cnt, u32 target) {
    if (threadIdx.x == 0) {
        while (__hip_atomic_load(cnt, __ATOMIC_RELAXED, __HIP_MEMORY_SCOPE_AGENT) < target)
            __builtin_amdgcn_s_sleep(1);
        __threadfence();   // acquire: invalidate stale L1/L2 before h / out0 reads
    }
    __syncthreads();
}

// Persistent layer runner. 8 waves/block. Weights held in VGPRs for the
// whole scan. Per step: x-part MFMA (no wait) -> spin on own h flag ->
// h-part MFMA -> LDS reduce across waves -> fused pointwise (c,h_old in
// registers) -> release fence -> arrive.
// JTP hidden units/block; NF = JTP*4/16 B-fragments; XC/HC = x/h K-chunks
// per wave (chunk = 32 k); NQ = pointwise slots/thread = B_*JTP/512.
template<int LAYER, int JTP, int XC, int HC, int NF, int NQ>
__device__ void run_layer(
    const u16* __restrict__ xin,      // L0: in_bf (T,B,IN); L1: out0_bf (T,B,H)
    const u16* __restrict__ Wih, const u16* __restrict__ Whh,
    const float* __restrict__ bsum, const float* __restrict__ mask,
    u16* __restrict__ hsl,            // this layer's (2,B,H) bf16 h slots
    u16* __restrict__ out_bf,         // L0: out0_bf; L1 unused
    float* __restrict__ dout,
    u32* cnt_own, u32* cnt_prev, int jblk, float* red)
{
    constexpr int KSTR = LAYER ? H_ : IN_;
    constexpr int RL = 4 * JTP + 1;           // padded reduce-row length
    constexpr unsigned NJB_OWN = LAYER ? 128u : 64u;

    const int tid  = threadIdx.x;
    const int w    = tid >> 6;
    const int lane = tid & 63;
    const int rm   = lane & 15;
    const int ks   = (lane >> 4) << 3;        // k sub-offset 0,8,16,24
    const int j0   = jblk * JTP;

    // B-fragment weight-row per fragment f, lane col rm:
    // cc = f*16+rm -> gate = cc/JTP, jl = cc%JTP -> W-row gate*H + j0 + jl
    int wrow[NF];
    #pragma unroll
    for (int f = 0; f < NF; ++f) {
        int cc = f * 16 + rm;
        wrow[f] = (cc / JTP) * H_ + j0 + (cc % JTP);
    }

    // ---- weight preload into registers (once) ----
    short8 wx[XC][NF], wh[HC][NF];
    #pragma unroll
    for (int i = 0; i < XC; ++i) {
        const int k0 = (w * XC + i) * 32;
        #pragma unroll
        for (int f = 0; f < NF; ++f)
            wx[i][f] = *reinterpret_cast<const short8*>(Wih + (size_t)wrow[f] * KSTR + k0 + ks);
    }
    #pragma unroll
    for (int i = 0; i < HC; ++i) {
        const int k0 = (w * HC + i) * 32;
        #pragma unroll
        for (int f = 0; f < NF; ++f)
            wh[i][f] = *reinterpret_cast<const short8*>(Whh + (size_t)wrow[f] * H_ + k0 + ks);
    }

    // bias preload (fixed per pointwise slot)
    float bsr[NQ][4];
    #pragma unroll
    for (int q = 0; q < NQ; ++q) {
        const int u = tid * NQ + q;
        const int jl = u % JTP;
        #pragma unroll
        for (int g = 0; g < 4; ++g)
            bsr[q][g] = bsum[g * H_ + j0 + jl];
    }

    float creg[NQ], hreg[NQ];
    #pragma unroll
    for (int q = 0; q < NQ; ++q) { creg[q] = 0.f; hreg[q] = 0.f; }

    for (int t = 0; t < T_; ++t) {
        // L1 needs out0[t] fully written (L0 has 64 blocks)
        if (LAYER == 1) spin_wait(cnt_prev, 64u * (u32)(t + 1));

        const u16* xt = xin + (size_t)t * B_ * KSTR;
        f32x4 acc[4][NF];
        #pragma unroll
        for (int a = 0; a < 4; ++a)
            #pragma unroll
            for (int f = 0; f < NF; ++f)
                acc[a][f] = (f32x4){0.f, 0.f, 0.f, 0.f};

        // ---- x-part (no recurrence dependency) ----
        #pragma unroll
        for (int i = 0; i < XC; ++i) {
            const int k0 = (w * XC + i) * 32;
            short8 afr[4];
            #pragma unroll
            for (int mi = 0; mi < 4; ++mi)
                afr[mi] = *reinterpret_cast<const short8*>(xt + (size_t)((mi << 4) + rm) * KSTR + k0 + ks);
            #pragma unroll
            for (int mi = 0; mi < 4; ++mi)
                #pragma unroll
                for (int f = 0; f < NF; ++f)
                    acc[mi][f] = __builtin_amdgcn_mfma_f32_16x16x32_bf16(afr[mi], wx[i][f], acc[mi][f], 0, 0, 0);
        }

        // ---- h-part (gated on own layer's previous step) ----
        if (t > 0) {
            spin_wait(cnt_own, NJB_OWN * (u32)t);
            const u16* hp = hsl + (size_t)((t + 1) & 1) * B_ * H_;
            #pragma unroll
            for (int i = 0; i < HC; ++i) {
                const int k0 = (w * HC + i) * 32;
                short8 afr[4];
                #pragma unroll
                for (int mi = 0; mi < 4; ++mi)
                    afr[mi] = *reinterpret_cast<const short8*>(hp + (size_t)((mi << 4) + rm) * H_ + k0 + ks);
                #pragma unroll
                for (int mi = 0; mi < 4; ++mi)
                    #pragma unroll
                    for (int f = 0; f < NF; ++f)
                        acc[mi][f] = __builtin_amdgcn_mfma_f32_16x16x32_bf16(afr[mi], wh[i][f], acc[mi][f], 0, 0, 0);
            }
        }

        // ---- cross-wave reduce via LDS ----
        // C layout (16x16x32): col = lane&15, row = (lane>>4)*4 + reg
        const int rb = (lane >> 4) << 2;
        #pragma unroll
        for (int mi = 0; mi < 4; ++mi)
            #pragma unroll
            for (int f = 0; f < NF; ++f)
                #pragma unroll
                for (int rr = 0; rr < 4; ++rr)
                    red[((w << 6) + (mi << 4) + rb + rr) * RL + (f << 4) + rm] = acc[mi][f][rr];
        __syncthreads();

        // ---- fused pointwise ----
        const float* mt = mask + (size_t)t * B_;
        u16* hw = hsl + (size_t)(t & 1) * B_ * H_;
        #pragma unroll
        for (int q = 0; q < NQ; ++q) {
            const int u = tid * NQ + q;
            const int b = u / JTP;
            const int jl = u % JTP;
            const int j = j0 + jl;
            float pre[4];
            #pragma unroll
            for (int g = 0; g < 4; ++g) {
                float s = 0.f;
                #pragma unroll
                for (int wv = 0; wv < 8; ++wv)
                    s += red[((wv << 6) + b) * RL + g * JTP + jl];
                pre[g] = s + bsr[q][g];
            }
            float ig = sigm(pre[0]);
            float fg = sigm(pre[1]);
            float gg = ftanh(pre[2]);
            float og = sigm(pre[3]);
            float c_old = creg[q], h_old = hreg[q];
            float mm = mt[b];
            float c_new = fg * c_old + ig * gg;
            float h_new = og * ftanh(c_new);
            h_new = mm * h_new + (1.f - mm) * h_old;
            c_new = mm * c_new + (1.f - mm) * c_old;
            creg[q] = c_new; hreg[q] = h_new;
            const int idx = b * H_ + j;
            hw[idx] = f2bf(h_new);
            if (LAYER == 0) out_bf[(size_t)t * B_ * H_ + idx] = f2bf(h_new);
            else            dout[(size_t)t * B_ * H_ + idx] = h_new;
            if (t == T_ - 1) {
                dout[(size_t)T_ * B_ * H_ + (size_t)LAYER * B_ * H_ + idx] = h_new;
                dout[(size_t)T_ * B_ * H_ + (size_t)(2 + LAYER) * B_ * H_ + idx] = c_new;
            }
        }

        // ---- release + arrive ----
        __threadfence();          // writeback h/out0 to coherence point
        __syncthreads();          // all threads' stores+fences done; also guards red reuse
        if (tid == 0) atomicAdd(cnt_own, 1u);
    }
}

// grid = 192 blocks x 512 threads: blocks [0,64) = layer0 (JT=16),
// [64,192) = layer1 (JT=8). All blocks need only 1 CU each -> co-resident
// with 64-CU margin (no cooperative launch required).
__global__ __launch_bounds__(512, 2) void lstm_persist(
    const u16* __restrict__ in_bf, u16* __restrict__ out0_bf,
    const u16* __restrict__ wih0, const u16* __restrict__ whh0,
    const u16* __restrict__ wih1, const u16* __restrict__ whh1,
    const float* __restrict__ bs0, const float* __restrict__ bs1,
    const float* __restrict__ mask, u16* __restrict__ hbf,
    float* __restrict__ dout, u32* __restrict__ flags)
{
    __shared__ float red[8 * 64 * 65];   // 130 KB; L1 path uses a 66 KB prefix
    const int bid = blockIdx.x;
    if (bid < 64)
        run_layer<0, 16, 2, 4, 4, 2>(in_bf, wih0, whh0, bs0, mask,
                                     hbf, out0_bf, dout,
                                     flags, flags + 32, bid, red);
    else
        run_layer<1, 8, 4, 4, 2, 1>(out0_bf, wih1, whh1, bs1, mask,
                                    hbf + 2 * B_ * H_, nullptr, dout,
                                    flags + 32, flags, bid - 64, red);
}

extern "C" void kernel_launch(void* const* d_in, const int* in_sizes, int n_in,
                              void* d_out, int out_size, void* d_ws, size_t ws_size,
                              hipStream_t stream) {
    const float* input_ = (const float*)d_in[0];
    const float* mask   = (const float*)d_in[1];
    const float* Wih0   = (const float*)d_in[2];
    const float* Whh0   = (const float*)d_in[3];
    const float* bih0   = (const float*)d_in[4];
    const float* bhh0   = (const float*)d_in[5];
    const float* Wih1   = (const float*)d_in[6];
    const float* Whh1   = (const float*)d_in[7];
    const float* bih1   = (const float*)d_in[8];
    const float* bhh1   = (const float*)d_in[9];
    float* dout = (float*)d_out;

    char* ws = (char*)d_ws;
    size_t off = 0;
    auto alloc = [&](size_t bytes) -> void* {
        void* p = ws + off;
        off += (bytes + 255) & ~(size_t)255;
        return p;
    };
    u16* in_bf   = (u16*)alloc((size_t)T_ * B_ * IN_ * 2);
    u16* out0_bf = (u16*)alloc((size_t)T_ * B_ * H_ * 2);
    u16* wih0    = (u16*)alloc((size_t)G4_ * IN_ * 2);
    u16* whh0    = (u16*)alloc((size_t)G4_ * H_ * 2);
    u16* wih1    = (u16*)alloc((size_t)G4_ * H_ * 2);
    u16* whh1    = (u16*)alloc((size_t)G4_ * H_ * 2);
    float* bs0   = (float*)alloc((size_t)G4_ * 4);
    float* bs1   = (float*)alloc((size_t)G4_ * 4);
    u16* hbf     = (u16*)alloc((size_t)4 * B_ * H_ * 2);   // 2 layers x 2 slots
    u32* flags   = (u32*)alloc(256);

    hipMemsetAsync(flags, 0, 256, stream);

    auto cvt = [&](const float* src, u16* dst, size_t n) {
        int blocks = (int)((n / 4 + 255) / 256);
        hipLaunchKernelGGL(f2b_kernel, dim3(blocks), dim3(256), 0, stream, src, dst, (int)n);
    };
    cvt(input_, in_bf, (size_t)T_ * B_ * IN_);
    cvt(Wih0, wih0, (size_t)G4_ * IN_);
    cvt(Whh0, whh0, (size_t)G4_ * H_);
    cvt(Wih1, wih1, (size_t)G4_ * H_);
    cvt(Whh1, whh1, (size_t)G4_ * H_);
    hipLaunchKernelGGL(bias_sum_kernel, dim3(16), dim3(256), 0, stream,
                       bih0, bhh0, bih1, bhh1, bs0, bs1);

    hipLaunchKernelGGL(lstm_persist, dim3(192), dim3(512), 0, stream,
                       in_bf, out0_bf, wih0, whh0, wih1, whh1,
                       bs0, bs1, mask, hbf, dout, flags);
}

// Round 4
// 9281.956 us; speedup vs baseline: 2.9403x; 2.9403x over previous
//
#include <hip/hip_runtime.h>
#include <hip/hip_bf16.h>

#define T_ 512
#define B_ 64
#define IN_ 512
#define H_ 1024
#define G4_ 4096

typedef unsigned short u16;
typedef unsigned int u32;
typedef unsigned long long u64;
typedef __attribute__((ext_vector_type(8))) short short8;
typedef __attribute__((ext_vector_type(4))) float f32x4;

__device__ __forceinline__ float sigm(float x) { return 1.0f / (1.0f + __expf(-x)); }
__device__ __forceinline__ float ftanh(float x) {
    float e = __expf(-2.0f * fabsf(x));
    float t = (1.0f - e) / (1.0f + e);
    return copysignf(t, x);
}
__device__ __forceinline__ u16 f2bf(float f) {
    unsigned int x = __float_as_uint(f);
    return (u16)((x + 0x7FFFu + ((x >> 16) & 1u)) >> 16);
}

// ---- system-scope (coherence-point) data movement: no fences needed ----
__device__ __forceinline__ short8 sysload8(const u16* p) {
    union { short8 v; u64 q[2]; } u;
    u.q[0] = __hip_atomic_load((const u64*)p,       __ATOMIC_RELAXED, __HIP_MEMORY_SCOPE_SYSTEM);
    u.q[1] = __hip_atomic_load((const u64*)(p + 4), __ATOMIC_RELAXED, __HIP_MEMORY_SCOPE_SYSTEM);
    return u.v;
}
__device__ __forceinline__ void sysstore32(u16* p, u32 v) {
    __hip_atomic_store((u32*)p, v, __ATOMIC_RELAXED, __HIP_MEMORY_SCOPE_SYSTEM);
}

// Wave-parallel arrival wait: lane i polls producer-block i's slot (64-byte
// spaced). Loop exits per-lane; wave reconverges when all 64 slots reached
// target. No cache ops: slots are system-scope atomics.
__device__ __forceinline__ void spin_wait_slots(u32* slots, u32 target) {
    if (threadIdx.x < 64) {
        u32* p = slots + threadIdx.x * 16;
        while (__hip_atomic_load(p, __ATOMIC_RELAXED, __HIP_MEMORY_SCOPE_SYSTEM) < target)
            __builtin_amdgcn_s_sleep(2);
    }
    __syncthreads();
}

__global__ void f2b_kernel(const float* __restrict__ in, u16* __restrict__ out, int n) {
    int i = (blockIdx.x * blockDim.x + threadIdx.x) * 4;
    if (i < n) {
        float4 v = *reinterpret_cast<const float4*>(in + i);
        out[i + 0] = f2bf(v.x);
        out[i + 1] = f2bf(v.y);
        out[i + 2] = f2bf(v.z);
        out[i + 3] = f2bf(v.w);
    }
}

__global__ void bias_sum_kernel(const float* __restrict__ bih0, const float* __restrict__ bhh0,
                                const float* __restrict__ bih1, const float* __restrict__ bhh1,
                                float* __restrict__ bs0, float* __restrict__ bs1) {
    int i = blockIdx.x * blockDim.x + threadIdx.x;
    if (i < G4_) {
        bs0[i] = bih0[i] + bhh0[i];
        bs1[i] = bih1[i] + bhh1[i];
    }
}

// Persistent layer runner: 64 blocks/layer, 8 waves/block, j-tile 16
// (64 W-rows/block). Weights pinned in registers for the whole scan.
// Cross-block h/out0 exchange via system-scope atomics (bypass L1/L2);
// sync via per-block slot stores + wave-parallel polling.
template<int LAYER, int XC>
__device__ void run_layer(
    const u16* __restrict__ xin,      // L0: in_bf (T,B,IN) cacheable; L1: out0_bf (sys-scope)
    const u16* __restrict__ Wih, const u16* __restrict__ Whh,
    const float* __restrict__ bsum, const float* __restrict__ mask,
    u16* __restrict__ hsl,            // this layer's (2,B,H) bf16 h ring
    u16* __restrict__ out_bf,         // L0: out0_bf; L1: unused
    float* __restrict__ dout,
    u32* slots_own, u32* slots_prev, int jblk, float* red)
{
    constexpr int KSTR = LAYER ? H_ : IN_;
    constexpr int HC = 4;             // h-K chunks/wave: 8w*4*32 = 1024
    constexpr int RL = 65;            // padded reduce-row length (64 cols + 1)

    const int tid  = threadIdx.x;
    const int w    = tid >> 6;
    const int lane = tid & 63;
    const int rm   = lane & 15;
    const int ks   = (lane >> 4) << 3;        // k sub-offset 0,8,16,24
    const int j0   = jblk * 16;

    // fragment f == gate f (j-tile 16): W-row = f*H + j0 + rm
    // ---- weight preload into registers (once, plain cacheable) ----
    short8 wx[XC][4], wh[HC][4];
    #pragma unroll
    for (int i = 0; i < XC; ++i) {
        const int k0 = (w * XC + i) * 32;
        #pragma unroll
        for (int f = 0; f < 4; ++f)
            wx[i][f] = *reinterpret_cast<const short8*>(Wih + (size_t)(f * H_ + j0 + rm) * KSTR + k0 + ks);
    }
    #pragma unroll
    for (int i = 0; i < HC; ++i) {
        const int k0 = (w * HC + i) * 32;
        #pragma unroll
        for (int f = 0; f < 4; ++f)
            wh[i][f] = *reinterpret_cast<const short8*>(Whh + (size_t)(f * H_ + j0 + rm) * H_ + k0 + ks);
    }

    // pointwise mapping: thread -> (batch b, j-pair jlp)
    const int pb  = tid >> 3;          // 0..63
    const int jlp = (tid & 7) << 1;    // 0,2,..,14

    float creg[2] = {0.f, 0.f}, hreg[2] = {0.f, 0.f};

    for (int t = 0; t < T_; ++t) {
        // L1 needs out0[t] complete (all 64 L0 blocks arrived t+1)
        if (LAYER == 1) spin_wait_slots(slots_prev, (u32)(t + 1));

        const u16* xt = xin + (size_t)t * B_ * KSTR;
        f32x4 acc[4][4];
        #pragma unroll
        for (int a = 0; a < 4; ++a)
            #pragma unroll
            for (int f = 0; f < 4; ++f)
                acc[a][f] = (f32x4){0.f, 0.f, 0.f, 0.f};

        // ---- x-part ----
        #pragma unroll
        for (int i = 0; i < XC; ++i) {
            const int k0 = (w * XC + i) * 32;
            short8 afr[4];
            #pragma unroll
            for (int mi = 0; mi < 4; ++mi) {
                const u16* p = xt + (size_t)((mi << 4) + rm) * KSTR + k0 + ks;
                afr[mi] = (LAYER == 0) ? *reinterpret_cast<const short8*>(p) : sysload8(p);
            }
            #pragma unroll
            for (int mi = 0; mi < 4; ++mi)
                #pragma unroll
                for (int f = 0; f < 4; ++f)
                    acc[mi][f] = __builtin_amdgcn_mfma_f32_16x16x32_bf16(afr[mi], wx[i][f], acc[mi][f], 0, 0, 0);
        }

        // ---- h-part (own recurrence, gated on all peer blocks' step t-1) ----
        if (t > 0) {
            spin_wait_slots(slots_own, (u32)t);
            const u16* hp = hsl + (size_t)((t + 1) & 1) * B_ * H_;
            #pragma unroll
            for (int i = 0; i < HC; ++i) {
                const int k0 = (w * HC + i) * 32;
                short8 afr[4];
                #pragma unroll
                for (int mi = 0; mi < 4; ++mi)
                    afr[mi] = sysload8(hp + (size_t)((mi << 4) + rm) * H_ + k0 + ks);
                #pragma unroll
                for (int mi = 0; mi < 4; ++mi)
                    #pragma unroll
                    for (int f = 0; f < 4; ++f)
                        acc[mi][f] = __builtin_amdgcn_mfma_f32_16x16x32_bf16(afr[mi], wh[i][f], acc[mi][f], 0, 0, 0);
            }
        }

        // ---- cross-wave reduce via LDS ----
        // C layout (16x16x32): col = lane&15, row = (lane>>4)*4 + reg
        const int rb = (lane >> 4) << 2;
        #pragma unroll
        for (int mi = 0; mi < 4; ++mi)
            #pragma unroll
            for (int f = 0; f < 4; ++f)
                #pragma unroll
                for (int rr = 0; rr < 4; ++rr)
                    red[((w << 6) + (mi << 4) + rb + rr) * RL + (f << 4) + rm] = acc[mi][f][rr];
        __syncthreads();

        // ---- fused pointwise: thread owns (pb, j0+jlp .. j0+jlp+1) ----
        const float mm = mask[(size_t)t * B_ + pb];
        u16* hw = hsl + (size_t)(t & 1) * B_ * H_;
        float hnew[2];
        #pragma unroll
        for (int q = 0; q < 2; ++q) {
            const int jl = jlp + q;
            float pre[4];
            #pragma unroll
            for (int g = 0; g < 4; ++g) {
                float s = 0.f;
                #pragma unroll
                for (int wv = 0; wv < 8; ++wv)
                    s += red[((wv << 6) + pb) * RL + (g << 4) + jl];
                pre[g] = s + bsum[g * H_ + j0 + jl];
            }
            float ig = sigm(pre[0]);
            float fg = sigm(pre[1]);
            float gg = ftanh(pre[2]);
            float og = sigm(pre[3]);
            float c_new = fg * creg[q] + ig * gg;
            float h_new = og * ftanh(c_new);
            h_new = mm * h_new + (1.f - mm) * hreg[q];
            c_new = mm * c_new + (1.f - mm) * creg[q];
            creg[q] = c_new; hreg[q] = h_new;
            hnew[q] = h_new;
        }
        const int idx = pb * H_ + j0 + jlp;
        const u32 hpack = (u32)f2bf(hnew[0]) | ((u32)f2bf(hnew[1]) << 16);
        sysstore32(hw + idx, hpack);
        if (LAYER == 0) {
            sysstore32(out_bf + (size_t)t * B_ * H_ + idx, hpack);
        } else {
            *reinterpret_cast<float2*>(dout + (size_t)t * B_ * H_ + idx) = make_float2(hnew[0], hnew[1]);
        }
        if (t == T_ - 1) {
            *reinterpret_cast<float2*>(dout + (size_t)T_ * B_ * H_ + (size_t)LAYER * B_ * H_ + idx)
                = make_float2(hnew[0], hnew[1]);
            *reinterpret_cast<float2*>(dout + (size_t)T_ * B_ * H_ + (size_t)(2 + LAYER) * B_ * H_ + idx)
                = make_float2(creg[0], creg[1]);
        }

        // ---- release: sc-stores acked -> barrier -> publish arrival ----
        asm volatile("s_waitcnt vmcnt(0)" ::: "memory");
        __syncthreads();
        if (tid == 0)
            __hip_atomic_store(slots_own + jblk * 16, (u32)(t + 1),
                               __ATOMIC_RELAXED, __HIP_MEMORY_SCOPE_SYSTEM);
    }
}

// grid = 128 blocks x 512 threads: [0,64) = layer0, [64,128) = layer1.
// 133 KB LDS -> 1 block/CU; 128 blocks <= 256 CUs -> all co-resident.
__global__ __launch_bounds__(512, 2) void lstm_persist(
    const u16* __restrict__ in_bf, u16* __restrict__ out0_bf,
    const u16* __restrict__ wih0, const u16* __restrict__ whh0,
    const u16* __restrict__ wih1, const u16* __restrict__ whh1,
    const float* __restrict__ bs0, const float* __restrict__ bs1,
    const float* __restrict__ mask, u16* __restrict__ hbf,
    float* __restrict__ dout, u32* __restrict__ slots)
{
    __shared__ float red[8 * 64 * 65];
    const int bid = blockIdx.x;
    if (bid < 64)
        run_layer<0, 2>(in_bf, wih0, whh0, bs0, mask,
                        hbf, out0_bf, dout, slots, slots + 1024, bid, red);
    else
        run_layer<1, 4>(out0_bf, wih1, whh1, bs1, mask,
                        hbf + 2 * B_ * H_, nullptr, dout, slots + 1024, slots, bid - 64, red);
}

extern "C" void kernel_launch(void* const* d_in, const int* in_sizes, int n_in,
                              void* d_out, int out_size, void* d_ws, size_t ws_size,
                              hipStream_t stream) {
    const float* input_ = (const float*)d_in[0];
    const float* mask   = (const float*)d_in[1];
    const float* Wih0   = (const float*)d_in[2];
    const float* Whh0   = (const float*)d_in[3];
    const float* bih0   = (const float*)d_in[4];
    const float* bhh0   = (const float*)d_in[5];
    const float* Wih1   = (const float*)d_in[6];
    const float* Whh1   = (const float*)d_in[7];
    const float* bih1   = (const float*)d_in[8];
    const float* bhh1   = (const float*)d_in[9];
    float* dout = (float*)d_out;

    char* ws = (char*)d_ws;
    size_t off = 0;
    auto alloc = [&](size_t bytes) -> void* {
        void* p = ws + off;
        off += (bytes + 255) & ~(size_t)255;
        return p;
    };
    u16* in_bf   = (u16*)alloc((size_t)T_ * B_ * IN_ * 2);
    u16* out0_bf = (u16*)alloc((size_t)T_ * B_ * H_ * 2);
    u16* wih0    = (u16*)alloc((size_t)G4_ * IN_ * 2);
    u16* whh0    = (u16*)alloc((size_t)G4_ * H_ * 2);
    u16* wih1    = (u16*)alloc((size_t)G4_ * H_ * 2);
    u16* whh1    = (u16*)alloc((size_t)G4_ * H_ * 2);
    float* bs0   = (float*)alloc((size_t)G4_ * 4);
    float* bs1   = (float*)alloc((size_t)G4_ * 4);
    u16* hbf     = (u16*)alloc((size_t)4 * B_ * H_ * 2);   // 2 layers x 2-slot ring
    u32* slots   = (u32*)alloc(2 * 1024 * 4);              // 2 layers x 64 slots x 64B

    hipMemsetAsync(slots, 0, 2 * 1024 * 4, stream);

    auto cvt = [&](const float* src, u16* dst, size_t n) {
        int blocks = (int)((n / 4 + 255) / 256);
        hipLaunchKernelGGL(f2b_kernel, dim3(blocks), dim3(256), 0, stream, src, dst, (int)n);
    };
    cvt(input_, in_bf, (size_t)T_ * B_ * IN_);
    cvt(Wih0, wih0, (size_t)G4_ * IN_);
    cvt(Whh0, whh0, (size_t)G4_ * H_);
    cvt(Wih1, wih1, (size_t)G4_ * H_);
    cvt(Whh1, whh1, (size_t)G4_ * H_);
    hipLaunchKernelGGL(bias_sum_kernel, dim3(16), dim3(256), 0, stream,
                       bih0, bhh0, bih1, bhh1, bs0, bs1);

    hipLaunchKernelGGL(lstm_persist, dim3(128), dim3(512), 0, stream,
                       in_bf, out0_bf, wih0, whh0, wih1, whh1,
                       bs0, bs1, mask, hbf, dout, slots);
}